// Round 9
// baseline (328.172 us; speedup 1.0000x reference)
//
#include <hip/hip_runtime.h>
#include <math.h>

#define NNODES 100000
#define NEDGES 1600000
#define EATOT  1700000   // edges + self loops
#define FIN    256
#define C1     64        // H*FH layer-1 output width
#define NH     8
#define C2     64
#define SLOPE  0.2f
#define LOG2E  1.4426950408889634f
#define QSCALE 8192.0f   // corr fixed-point scale (15-bit signed range)

#define SCAN_BLOCKS 98   // ceil(NNODES / 1024)

typedef __attribute__((ext_vector_type(8))) short short8;
typedef __attribute__((ext_vector_type(4))) float f32x4;

__device__ __forceinline__ void edge_sdc(int e, const int* __restrict__ ei,
                                         const float* __restrict__ ew,
                                         int& s, int& d, float& corr){
  if (e < NEDGES){ s = ei[e]; d = ei[NEDGES + e]; corr = 1.0f - 1.0f / ew[e]; }
  else { s = e - NEDGES; d = s; corr = 0.0f; }
}

__device__ __forceinline__ unsigned short f2bf(float f){
  unsigned u = __float_as_uint(f);
  unsigned r = (u + 0x7FFFu + ((u >> 16) & 1u)) >> 16;   // RNE
  return (unsigned short)r;
}

// ---------------- CSR build ----------------
__global__ void k_zero(int* __restrict__ deg){
  int i = blockIdx.x * blockDim.x + threadIdx.x;
  if (i < NNODES) deg[i] = 0;
}

__global__ void k_hist(const int* __restrict__ ei, int* __restrict__ deg,
                       int* __restrict__ rank){
  int e = blockIdx.x * blockDim.x + threadIdx.x;
  if (e >= EATOT) return;
  int d = (e < NEDGES) ? ei[NEDGES + e] : (e - NEDGES);
  rank[e] = atomicAdd(&deg[d], 1);
}

__global__ void k_scan_partial(const int* __restrict__ deg, int* __restrict__ partials){
  __shared__ int sh[256];
  int b = blockIdx.x, t = threadIdx.x;
  int base = b * 1024 + t * 4;
  int sum = 0;
  #pragma unroll
  for (int k = 0; k < 4; ++k){ int idx = base + k; if (idx < NNODES) sum += deg[idx]; }
  sh[t] = sum; __syncthreads();
  for (int off = 128; off > 0; off >>= 1){
    if (t < off) sh[t] += sh[t + off];
    __syncthreads();
  }
  if (t == 0) partials[b] = sh[0];
}

__global__ void k_scan_partials(int* __restrict__ partials){
  __shared__ int sh[128];
  int t = threadIdx.x;
  int v = (t < SCAN_BLOCKS) ? partials[t] : 0;
  sh[t] = v; __syncthreads();
  for (int off = 1; off < 128; off <<= 1){
    int y = (t >= off) ? sh[t - off] : 0;
    __syncthreads();
    sh[t] += y;
    __syncthreads();
  }
  if (t < SCAN_BLOCKS) partials[t] = sh[t] - v;   // exclusive
}

__global__ void k_scan_final(const int* __restrict__ deg, const int* __restrict__ partpre,
                             int* __restrict__ rowptr){
  __shared__ int sh[256];
  int b = blockIdx.x, t = threadIdx.x;
  int base = b * 1024 + t * 4;
  int v[4]; int sum = 0;
  #pragma unroll
  for (int k = 0; k < 4; ++k){ int idx = base + k; v[k] = (idx < NNODES) ? deg[idx] : 0; sum += v[k]; }
  sh[t] = sum; __syncthreads();
  for (int off = 1; off < 256; off <<= 1){
    int y = (t >= off) ? sh[t - off] : 0;
    __syncthreads();
    sh[t] += y;
    __syncthreads();
  }
  int run = sh[t] - sum + partpre[b];
  #pragma unroll
  for (int k = 0; k < 4; ++k){
    int idx = base + k;
    if (idx < NNODES) rowptr[idx] = run;
    run += v[k];
  }
  if (b == gridDim.x - 1 && t == 255) rowptr[NNODES] = run;
}

// placement: no atomic; packed 4B record = qcorr(15b signed)<<17 | src(17b)
__global__ void k_place(const int* __restrict__ ei, const float* __restrict__ ew,
                        const int* __restrict__ rank, const int* __restrict__ rowptr,
                        int* __restrict__ rec){
  int e = blockIdx.x * blockDim.x + threadIdx.x;
  if (e >= EATOT) return;
  int s, d; float corr;
  edge_sdc(e, ei, ew, s, d, corr);
  int pos = rowptr[d] + rank[e];
  int q = __float2int_rn(corr * (LOG2E * QSCALE));
  rec[pos] = (int)(((unsigned)q << 17) | (unsigned)s);
}

// ---------------- weight split: W[K][64] fp32 -> Wt_hi/Wt_lo[64][K] bf16 ----------------
__global__ void k_splitw(const float* __restrict__ W, short* __restrict__ th,
                         short* __restrict__ tl, int K){
  int idx = blockIdx.x * blockDim.x + threadIdx.x;
  if (idx >= K * 64) return;
  int k = idx >> 6, c = idx & 63;
  float w = W[idx];
  unsigned int b = __float_as_uint(w);
  unsigned short h = (unsigned short)(b >> 16);
  float hf = __uint_as_float(b & 0xffff0000u);
  float rem = w - hf;
  unsigned short lo = (unsigned short)(__float_as_uint(rem) >> 16);
  th[c * K + k] = (short)h;
  tl[c * K + k] = (short)lo;
}

// ------------- shared epilogue: C-write + fused logits (pre-scaled by log2e) -----------
template<int HEADS>
__device__ __forceinline__ void gemm_epilogue(
    f32x4 (&acc)[4], int lane, int rowg, int M,
    const float* __restrict__ asrc, const float* __restrict__ adst,
    unsigned short* __restrict__ Hout, float* __restrict__ alsrc,
    float* __restrict__ aldst)
{
  int l15 = lane & 15;
  #pragma unroll
  for (int c = 0; c < 4; ++c){
    #pragma unroll
    for (int reg = 0; reg < 4; ++reg){
      int r = rowg + reg;
      if (r < M) Hout[(size_t)r * 64 + c * 16 + l15] = f2bf(acc[c][reg]);
    }
  }
  float asc[4], adc[4];
  #pragma unroll
  for (int c = 0; c < 4; ++c){
    asc[c] = asrc[c * 16 + l15] * LOG2E;
    adc[c] = adst[c * 16 + l15] * LOG2E;
  }
  if (HEADS == 8){
    #pragma unroll
    for (int reg = 0; reg < 4; ++reg){
      int r = rowg + reg;
      #pragma unroll
      for (int c = 0; c < 4; ++c){
        float ps = acc[c][reg] * asc[c];
        float pd = acc[c][reg] * adc[c];
        ps += __shfl_xor(ps, 1, 64); ps += __shfl_xor(ps, 2, 64); ps += __shfl_xor(ps, 4, 64);
        pd += __shfl_xor(pd, 1, 64); pd += __shfl_xor(pd, 2, 64); pd += __shfl_xor(pd, 4, 64);
        if ((l15 & 7) == 0 && r < M){
          int head = c * 2 + (l15 >> 3);
          alsrc[r * NH + head] = ps;
          aldst[r * NH + head] = pd;
        }
      }
    }
  } else {
    #pragma unroll
    for (int reg = 0; reg < 4; ++reg){
      int r = rowg + reg;
      float ps = 0.0f, pd = 0.0f;
      #pragma unroll
      for (int c = 0; c < 4; ++c){
        ps = fmaf(acc[c][reg], asc[c], ps);
        pd = fmaf(acc[c][reg], adc[c], pd);
      }
      ps += __shfl_xor(ps, 1, 64); ps += __shfl_xor(ps, 2, 64);
      ps += __shfl_xor(ps, 4, 64); ps += __shfl_xor(ps, 8, 64);
      pd += __shfl_xor(pd, 1, 64); pd += __shfl_xor(pd, 2, 64);
      pd += __shfl_xor(pd, 4, 64); pd += __shfl_xor(pd, 8, 64);
      if (l15 == 0 && r < M){ alsrc[r] = ps; aldst[r] = pd; }
    }
  }
}

// ---------------- layer-1 GEMM: X fp32 staged via global_load_lds (swizzled) ----------
// 64-row tile per block; x[64][256] fp32 = 64KB LDS; B hi/lo from global (L2-hot).
// Swizzle: 16B-unit u' = u ^ (row&7), applied on the GLOBAL source (m173 pattern).
__global__ __launch_bounds__(256) void k_gemm1(
    const float* __restrict__ X, const short* __restrict__ Bth,
    const short* __restrict__ Btl, const float* __restrict__ asrc,
    const float* __restrict__ adst, unsigned short* __restrict__ Hout,
    float* __restrict__ alsrc, float* __restrict__ aldst, int M)
{
  __shared__ float xlds[64 * 256];   // 64 KB
  int lane = threadIdx.x & 63;
  int wave = threadIdx.x >> 6;
  int tilebase = blockIdx.x * 64;

  // stage: each wave issues 16 rows (1 KB each, fully coalesced, async)
  #pragma unroll
  for (int t = 0; t < 16; ++t){
    int r = wave * 16 + t;
    int rg = tilebase + r; if (rg > M - 1) rg = M - 1;
    unsigned u = (unsigned)(lane ^ (r & 7));          // pre-swizzled source unit
    __builtin_amdgcn_global_load_lds(
        (const unsigned int*)(X + (size_t)rg * FIN + u * 4),
        (unsigned int*)&xlds[r * 256], 16, 0, 0);
  }
  __syncthreads();   // drains vmcnt before barrier

  int l15 = lane & 15;
  int rl = wave * 16 + l15;
  int rs = rl & 7;

  f32x4 acc[4] = {f32x4{0,0,0,0}, f32x4{0,0,0,0}, f32x4{0,0,0,0}, f32x4{0,0,0,0}};

  #pragma unroll
  for (int ks = 0; ks < FIN / 32; ++ks){
    int k0 = ks * 32 + (lane >> 4) * 8;               // logical f32 k-offset
    unsigned U = (unsigned)(k0 >> 2);                 // 16B unit index (even)
    float4 xa = *(const float4*)&xlds[rl * 256 + ((U ^ rs) << 2)];
    float4 xb = *(const float4*)&xlds[rl * 256 + (((U + 1) ^ rs) << 2)];
    float xs[8] = {xa.x, xa.y, xa.z, xa.w, xb.x, xb.y, xb.z, xb.w};
    short8 ah, al;
    #pragma unroll
    for (int j = 0; j < 8; ++j){
      unsigned u = __float_as_uint(xs[j]);
      ah[j] = (short)(u >> 16);
      float hf = __uint_as_float(u & 0xffff0000u);
      al[j] = (short)(__float_as_uint(xs[j] - hf) >> 16);
    }
    #pragma unroll
    for (int c = 0; c < 4; ++c){
      unsigned boff = (unsigned)(c * 16 + l15) * FIN + k0;
      short8 bh = *(const short8*)&Bth[boff];
      short8 bl = *(const short8*)&Btl[boff];
      acc[c] = __builtin_amdgcn_mfma_f32_16x16x32_bf16(ah, bh, acc[c], 0, 0, 0);
      acc[c] = __builtin_amdgcn_mfma_f32_16x16x32_bf16(ah, bl, acc[c], 0, 0, 0);
      acc[c] = __builtin_amdgcn_mfma_f32_16x16x32_bf16(al, bh, acc[c], 0, 0, 0);
    }
  }

  int rowg = tilebase + wave * 16 + (lane >> 4) * 4;
  gemm_epilogue<NH>(acc, lane, rowg, M, asrc, adst, Hout, alsrc, aldst);
}

// ---------------- layer-2 GEMM: A is pre-split bf16 hi/lo planes (no conversion) ------
__global__ __launch_bounds__(256) void k_gemm2(
    const unsigned short* __restrict__ Ah, const unsigned short* __restrict__ Al,
    const short* __restrict__ Bth, const short* __restrict__ Btl,
    const float* __restrict__ asrc, const float* __restrict__ adst,
    unsigned short* __restrict__ Hout, float* __restrict__ alsrc,
    float* __restrict__ aldst, int M)
{
  __shared__ unsigned short ahl[64 * 64];  // 8 KB hi plane (rows of 64 bf16 = 8 units)
  __shared__ unsigned short alo[64 * 64];  // 8 KB lo plane
  int lane = threadIdx.x & 63;
  int wave = threadIdx.x >> 6;
  int tilebase = blockIdx.x * 64;

  // stage both planes: 8 issues each (8 rows per issue), 2 per wave per plane
  #pragma unroll
  for (int t = 0; t < 2; ++t){
    int p = wave * 2 + t;
    int r = p * 8 + (lane >> 3);
    int rg = tilebase + r; if (rg > M - 1) rg = M - 1;
    unsigned u = (unsigned)((lane & 7) ^ (r & 7));
    __builtin_amdgcn_global_load_lds(
        (const unsigned int*)(Ah + (size_t)rg * 64 + u * 8),
        (unsigned int*)&ahl[p * 512], 16, 0, 0);
    __builtin_amdgcn_global_load_lds(
        (const unsigned int*)(Al + (size_t)rg * 64 + u * 8),
        (unsigned int*)&alo[p * 512], 16, 0, 0);
  }
  __syncthreads();

  int l15 = lane & 15;
  int rl = wave * 16 + l15;
  int rs = rl & 7;

  f32x4 acc[4] = {f32x4{0,0,0,0}, f32x4{0,0,0,0}, f32x4{0,0,0,0}, f32x4{0,0,0,0}};

  #pragma unroll
  for (int ks = 0; ks < 2; ++ks){
    int k0 = ks * 32 + (lane >> 4) * 8;               // short offset
    unsigned U = (unsigned)(k0 >> 3);                 // 16B unit
    short8 ah = *(const short8*)&ahl[rl * 64 + ((U ^ rs) << 3)];
    short8 al = *(const short8*)&alo[rl * 64 + ((U ^ rs) << 3)];
    #pragma unroll
    for (int c = 0; c < 4; ++c){
      unsigned boff = (unsigned)(c * 16 + l15) * C1 + k0;
      short8 bh = *(const short8*)&Bth[boff];
      short8 bl = *(const short8*)&Btl[boff];
      acc[c] = __builtin_amdgcn_mfma_f32_16x16x32_bf16(ah, bh, acc[c], 0, 0, 0);
      acc[c] = __builtin_amdgcn_mfma_f32_16x16x32_bf16(ah, bl, acc[c], 0, 0, 0);
      acc[c] = __builtin_amdgcn_mfma_f32_16x16x32_bf16(al, bh, acc[c], 0, 0, 0);
    }
  }

  int rowg = tilebase + wave * 16 + (lane >> 4) * 4;
  gemm_epilogue<1>(acc, lane, rowg, M, asrc, adst, Hout, alsrc, aldst);
}

// ---------------- aggregation: no-max softmax, 8-wide chunked MLP, one wave/node -------
// SPLIT_OUT: write bf16 hi/lo planes (layer1, feeds gemm2); else fp32 out (final).
template<int HEADS, bool DO_ELU, bool SPLIT_OUT>
__global__ __launch_bounds__(256) void k_agg(
    const int* __restrict__ rec, const int* __restrict__ rowptr,
    const unsigned short* __restrict__ hbuf,
    const float* __restrict__ alsrc, const float* __restrict__ aldst,
    const float* __restrict__ bias, float* __restrict__ outF,
    unsigned short* __restrict__ outH, unsigned short* __restrict__ outL){
  int tid = blockIdx.x * blockDim.x + threadIdx.x;
  int d = tid >> 6;
  int c = threadIdx.x & 63;
  if (d >= NNODES) return;
  d = __builtin_amdgcn_readfirstlane(d);      // wave-uniform -> scalar segment walk
  int beg = rowptr[d], end = rowptr[d + 1];
  int h = (HEADS == 8) ? (c >> 3) : 0;
  float ad = aldst[(size_t)d * HEADS + h];
  float s = 0.0f, acc = 0.0f;

  auto body = [&](int w, float a, float hv){
    float v = a + ad;
    v = fmaxf(v, v * SLOPE);                           // leakyrelu (slope<1)
    v += (float)(w >> 17) * (1.0f / QSCALE);           // corr (pre-scaled by log2e)
    v = fminf(v, 60.0f);                               // overflow guard
    float e = __builtin_amdgcn_exp2f(v);
    s += e;
    acc = fmaf(e, hv, acc);
  };

  int j = beg;
  for (; j + 8 <= end; j += 8){
    int w[8]; float a[8], hv[8];
    #pragma unroll
    for (int i = 0; i < 8; ++i) w[i] = rec[j + i];
    #pragma unroll
    for (int i = 0; i < 8; ++i){
      unsigned si = (unsigned)w[i] & 0x1FFFFu;
      a[i] = alsrc[si * HEADS + h];
      hv[i] = __uint_as_float((unsigned)hbuf[si * 64 + c] << 16);
    }
    #pragma unroll
    for (int i = 0; i < 8; ++i) body(w[i], a[i], hv[i]);
  }
  for (; j < end; ++j){
    int w = rec[j];
    unsigned sj = (unsigned)w & 0x1FFFFu;
    float a = alsrc[sj * HEADS + h];
    float hv = __uint_as_float((unsigned)hbuf[sj * 64 + c] << 16);
    body(w, a, hv);
  }

  float o = acc / (s + 1e-16f) + bias[c];
  if (DO_ELU) o = (o > 0.0f) ? o : (__expf(o) - 1.0f);
  if (SPLIT_OUT){
    unsigned u = __float_as_uint(o);
    outH[(size_t)d * 64 + c] = (unsigned short)(u >> 16);     // truncated hi
    float hf = __uint_as_float(u & 0xffff0000u);
    outL[(size_t)d * 64 + c] = (unsigned short)(__float_as_uint(o - hf) >> 16);
  } else {
    outF[(size_t)d * 64 + c] = o;
  }
}

extern "C" void kernel_launch(void* const* d_in, const int* in_sizes, int n_in,
                              void* d_out, int out_size, void* d_ws, size_t ws_size,
                              hipStream_t stream) {
  const float* x    = (const float*)d_in[0];
  const int*   ei   = (const int*)d_in[1];
  const float* ew   = (const float*)d_in[2];
  const float* W1   = (const float*)d_in[3];
  const float* as1  = (const float*)d_in[4];
  const float* ad1  = (const float*)d_in[5];
  const float* b1   = (const float*)d_in[6];
  const float* W2   = (const float*)d_in[7];
  const float* as2  = (const float*)d_in[8];
  const float* ad2  = (const float*)d_in[9];
  const float* b2   = (const float*)d_in[10];
  float* dout = (float*)d_out;

  float* ws = (float*)d_ws;
  size_t off = 0;
  auto alloc = [&](size_t nfloats) -> float* {
    float* p = ws + off;
    off += (nfloats + 15) & ~(size_t)15;
    return p;
  };
  unsigned short* h1 = (unsigned short*)alloc((size_t)NNODES * C1 / 2);  // bf16, 12.8MB
  unsigned short* o1h = (unsigned short*)alloc((size_t)NNODES * C1 / 2); // out1 hi plane
  unsigned short* o1l = (unsigned short*)alloc((size_t)NNODES * C1 / 2); // out1 lo plane
  float* alsrc1  = alloc((size_t)NNODES * NH);
  float* aldst1  = alloc((size_t)NNODES * NH);
  float* alsrc2  = alloc(NNODES);
  float* aldst2  = alloc(NNODES);
  int*   deg     = (int*)alloc(NNODES);
  int*   rowptr  = (int*)alloc(NNODES + 1);
  int*   rank    = (int*)alloc(EATOT);           // 6.8MB
  int*   partials= (int*)alloc(SCAN_BLOCKS + 16);
  int*   rec     = (int*)alloc(EATOT);           // 6.8MB packed records
  short* wt1h    = (short*)alloc(64 * FIN / 2);
  short* wt1l    = (short*)alloc(64 * FIN / 2);
  short* wt2h    = (short*)alloc(64 * C1 / 2);
  short* wt2l    = (short*)alloc(64 * C1 / 2);
  unsigned short* h2 = h1;   // h1 dead after k_agg1

  const int BS = 256;
  int egrid = (EATOT + BS - 1) / BS;
  int ngrid = (NNODES + BS - 1) / BS;

  // ---- weight splits ----
  hipLaunchKernelGGL(k_splitw, dim3((FIN * 64 + BS - 1) / BS), dim3(BS), 0, stream,
                     W1, wt1h, wt1l, FIN);
  hipLaunchKernelGGL(k_splitw, dim3((C1 * 64 + BS - 1) / BS), dim3(BS), 0, stream,
                     W2, wt2h, wt2l, C1);

  // ---- CSR build (dst-sorted, atomic-free placement) ----
  hipLaunchKernelGGL(k_zero,          dim3(ngrid), dim3(BS), 0, stream, deg);
  hipLaunchKernelGGL(k_hist,          dim3(egrid), dim3(BS), 0, stream, ei, deg, rank);
  hipLaunchKernelGGL(k_scan_partial,  dim3(SCAN_BLOCKS), dim3(BS), 0, stream, deg, partials);
  hipLaunchKernelGGL(k_scan_partials, dim3(1), dim3(128), 0, stream, partials);
  hipLaunchKernelGGL(k_scan_final,    dim3(SCAN_BLOCKS), dim3(BS), 0, stream, deg, partials, rowptr);
  hipLaunchKernelGGL(k_place,         dim3(egrid), dim3(BS), 0, stream, ei, ew, rank, rowptr, rec);

  int ntiles = (NNODES + 63) / 64;               // 1563
  int agrid  = (NNODES * 64 + BS - 1) / BS;

  // ---- layer 1 ----
  hipLaunchKernelGGL(k_gemm1, dim3(ntiles), dim3(BS), 0, stream,
                     x, wt1h, wt1l, as1, ad1, h1, alsrc1, aldst1, NNODES);
  hipLaunchKernelGGL((k_agg<NH, true, true>), dim3(agrid), dim3(BS), 0, stream,
                     rec, rowptr, h1, alsrc1, aldst1, b1, (float*)nullptr, o1h, o1l);

  // ---- layer 2 ----
  hipLaunchKernelGGL(k_gemm2, dim3(ntiles), dim3(BS), 0, stream,
                     o1h, o1l, wt2h, wt2l, as2, ad2, h2, alsrc2, aldst2, NNODES);
  hipLaunchKernelGGL((k_agg<1, false, false>), dim3(agrid), dim3(BS), 0, stream,
                     rec, rowptr, h2, alsrc2, aldst2, b2, dout,
                     (unsigned short*)nullptr, (unsigned short*)nullptr);
}

// Round 10
// 277.225 us; speedup vs baseline: 1.1838x; 1.1838x over previous
//
#include <hip/hip_runtime.h>
#include <math.h>

#define NNODES 100000
#define NEDGES 1600000
#define EATOT  1700000   // edges + self loops
#define FIN    256
#define C1     64        // H*FH layer-1 output width
#define NH     8
#define C2     64
#define SLOPE  0.2f
#define LOG2E  1.4426950408889634f
#define QSCALE 8192.0f   // corr fixed-point scale (15-bit signed range)

#define SCAN_BLOCKS 98   // ceil(NNODES / 1024)
#define NT1 3125         // gemm1 tiles (32 rows each, exact: 32*3125 = 100000)
#define NT2 1563         // gemm2 tiles (64 rows each)
#define GGRID 512        // grid for both gemms (2 blocks/CU resident)

typedef __attribute__((ext_vector_type(8))) short short8;
typedef __attribute__((ext_vector_type(4))) float f32x4;

__device__ __forceinline__ void edge_sdc(int e, const int* __restrict__ ei,
                                         const float* __restrict__ ew,
                                         int& s, int& d, float& corr){
  if (e < NEDGES){ s = ei[e]; d = ei[NEDGES + e]; corr = 1.0f - 1.0f / ew[e]; }
  else { s = e - NEDGES; d = s; corr = 0.0f; }
}

__device__ __forceinline__ unsigned short f2bf(float f){
  unsigned u = __float_as_uint(f);
  unsigned r = (u + 0x7FFFu + ((u >> 16) & 1u)) >> 16;   // RNE
  return (unsigned short)r;
}

// ---------------- CSR build ----------------
__global__ void k_zero(int* __restrict__ deg){
  int i = blockIdx.x * blockDim.x + threadIdx.x;
  if (i < NNODES) deg[i] = 0;
}

__global__ void k_hist(const int* __restrict__ ei, int* __restrict__ deg,
                       int* __restrict__ rank){
  int e = blockIdx.x * blockDim.x + threadIdx.x;
  if (e >= EATOT) return;
  int d = (e < NEDGES) ? ei[NEDGES + e] : (e - NEDGES);
  rank[e] = atomicAdd(&deg[d], 1);
}

__global__ void k_scan_partial(const int* __restrict__ deg, int* __restrict__ partials){
  __shared__ int sh[256];
  int b = blockIdx.x, t = threadIdx.x;
  int base = b * 1024 + t * 4;
  int sum = 0;
  #pragma unroll
  for (int k = 0; k < 4; ++k){ int idx = base + k; if (idx < NNODES) sum += deg[idx]; }
  sh[t] = sum; __syncthreads();
  for (int off = 128; off > 0; off >>= 1){
    if (t < off) sh[t] += sh[t + off];
    __syncthreads();
  }
  if (t == 0) partials[b] = sh[0];
}

__global__ void k_scan_partials(int* __restrict__ partials){
  __shared__ int sh[128];
  int t = threadIdx.x;
  int v = (t < SCAN_BLOCKS) ? partials[t] : 0;
  sh[t] = v; __syncthreads();
  for (int off = 1; off < 128; off <<= 1){
    int y = (t >= off) ? sh[t - off] : 0;
    __syncthreads();
    sh[t] += y;
    __syncthreads();
  }
  if (t < SCAN_BLOCKS) partials[t] = sh[t] - v;   // exclusive
}

__global__ void k_scan_final(const int* __restrict__ deg, const int* __restrict__ partpre,
                             int* __restrict__ rowptr){
  __shared__ int sh[256];
  int b = blockIdx.x, t = threadIdx.x;
  int base = b * 1024 + t * 4;
  int v[4]; int sum = 0;
  #pragma unroll
  for (int k = 0; k < 4; ++k){ int idx = base + k; v[k] = (idx < NNODES) ? deg[idx] : 0; sum += v[k]; }
  sh[t] = sum; __syncthreads();
  for (int off = 1; off < 256; off <<= 1){
    int y = (t >= off) ? sh[t - off] : 0;
    __syncthreads();
    sh[t] += y;
    __syncthreads();
  }
  int run = sh[t] - sum + partpre[b];
  #pragma unroll
  for (int k = 0; k < 4; ++k){
    int idx = base + k;
    if (idx < NNODES) rowptr[idx] = run;
    run += v[k];
  }
  if (b == gridDim.x - 1 && t == 255) rowptr[NNODES] = run;
}

// placement: no atomic; packed 4B record = qcorr(15b signed)<<17 | src(17b)
__global__ void k_place(const int* __restrict__ ei, const float* __restrict__ ew,
                        const int* __restrict__ rank, const int* __restrict__ rowptr,
                        int* __restrict__ rec){
  int e = blockIdx.x * blockDim.x + threadIdx.x;
  if (e >= EATOT) return;
  int s, d; float corr;
  edge_sdc(e, ei, ew, s, d, corr);
  int pos = rowptr[d] + rank[e];
  int q = __float2int_rn(corr * (LOG2E * QSCALE));
  rec[pos] = (int)(((unsigned)q << 17) | (unsigned)s);
}

// ---------------- weight split: W[K][64] fp32 -> Wt_hi/Wt_lo[64][K] bf16 ----------------
__global__ void k_splitw(const float* __restrict__ W, short* __restrict__ th,
                         short* __restrict__ tl, int K){
  int idx = blockIdx.x * blockDim.x + threadIdx.x;
  if (idx >= K * 64) return;
  int k = idx >> 6, c = idx & 63;
  float w = W[idx];
  unsigned int b = __float_as_uint(w);
  unsigned short h = (unsigned short)(b >> 16);
  float hf = __uint_as_float(b & 0xffff0000u);
  float rem = w - hf;
  unsigned short lo = (unsigned short)(__float_as_uint(rem) >> 16);
  th[c * K + k] = (short)h;
  tl[c * K + k] = (short)lo;
}

// ---------------- layer-1 GEMM: zero VMEM in K-loop -------------------------------------
// B (W^T hi/lo) in registers via col-pair split: wave w -> rows (w>>1)*16.., cols (w&1)*32..
// x double-buffered via global_load_lds (32-row fp32 tiles), source-swizzled.
__global__ __launch_bounds__(256, 2) void k_gemm1(
    const float* __restrict__ X, const short* __restrict__ Bth,
    const short* __restrict__ Btl, const float* __restrict__ asrc,
    const float* __restrict__ adst, unsigned short* __restrict__ Hout,
    float* __restrict__ alsrc, float* __restrict__ aldst)
{
  __shared__ float xbuf[2][32 * 256];   // 2 x 32KB
  const int lane = threadIdx.x & 63;
  const int wave = threadIdx.x >> 6;
  const int l15 = lane & 15;
  const int kg = lane >> 4;
  const int cp = wave & 1;              // col-pair: cols cp*32 .. cp*32+31
  const int rh = wave >> 1;             // row-half: rows rh*16 .. rh*16+15
  const int rl = rh * 16 + l15;
  const int rs = rl & 7;

  // B fragments in registers (loaded once per block, L2-hot)
  short8 bh[8][2], bl[8][2];
  #pragma unroll
  for (int ks = 0; ks < 8; ++ks){
    #pragma unroll
    for (int cc = 0; cc < 2; ++cc){
      unsigned boff = (unsigned)((cp * 2 + cc) * 16 + l15) * FIN + ks * 32 + kg * 8;
      bh[ks][cc] = *(const short8*)&Bth[boff];
      bl[ks][cc] = *(const short8*)&Btl[boff];
    }
  }
  float ascv[2], adcv[2];
  #pragma unroll
  for (int cc = 0; cc < 2; ++cc){
    ascv[cc] = asrc[(cp * 2 + cc) * 16 + l15] * LOG2E;
    adcv[cc] = adst[(cp * 2 + cc) * 16 + l15] * LOG2E;
  }

  const int t0 = blockIdx.x;
  // prologue: stage tile t0 into buf 0 (wave w stages rows w*8..w*8+7)
  #pragma unroll
  for (int t = 0; t < 8; ++t){
    int r = wave * 8 + t;
    unsigned u = (unsigned)(lane ^ (r & 7));        // pre-swizzled source unit
    __builtin_amdgcn_global_load_lds(
        (const unsigned int*)(X + (size_t)(t0 * 32 + r) * FIN + u * 4),
        (unsigned int*)&xbuf[0][r * 256], 16, 0, 0);
  }

  int cur = 0;
  for (int ti = t0; ti < NT1; ti += GGRID){
    __syncthreads();                                 // buf[cur] ready (vmcnt drain)
    int nxt = ti + GGRID;
    if (nxt < NT1){                                  // async prefetch under compute
      #pragma unroll
      for (int t = 0; t < 8; ++t){
        int r = wave * 8 + t;
        unsigned u = (unsigned)(lane ^ (r & 7));
        __builtin_amdgcn_global_load_lds(
            (const unsigned int*)(X + (size_t)(nxt * 32 + r) * FIN + u * 4),
            (unsigned int*)&xbuf[cur ^ 1][r * 256], 16, 0, 0);
      }
    }

    f32x4 acc[2] = {f32x4{0,0,0,0}, f32x4{0,0,0,0}};
    #pragma unroll
    for (int ks = 0; ks < 8; ++ks){
      int k0 = ks * 32 + kg * 8;
      unsigned U = (unsigned)(k0 >> 2);              // 16B unit (even)
      float4 xa = *(const float4*)&xbuf[cur][rl * 256 + ((U ^ rs) << 2)];
      float4 xb = *(const float4*)&xbuf[cur][rl * 256 + (((U + 1) ^ rs) << 2)];
      float xs[8] = {xa.x, xa.y, xa.z, xa.w, xb.x, xb.y, xb.z, xb.w};
      short8 ah, al;
      #pragma unroll
      for (int j = 0; j < 8; ++j){
        unsigned u = __float_as_uint(xs[j]);
        ah[j] = (short)(u >> 16);
        float hf = __uint_as_float(u & 0xffff0000u);
        al[j] = (short)(__float_as_uint(xs[j] - hf) >> 16);
      }
      #pragma unroll
      for (int cc = 0; cc < 2; ++cc){
        acc[cc] = __builtin_amdgcn_mfma_f32_16x16x32_bf16(ah, bh[ks][cc], acc[cc], 0, 0, 0);
        acc[cc] = __builtin_amdgcn_mfma_f32_16x16x32_bf16(ah, bl[ks][cc], acc[cc], 0, 0, 0);
        acc[cc] = __builtin_amdgcn_mfma_f32_16x16x32_bf16(al, bh[ks][cc], acc[cc], 0, 0, 0);
      }
    }

    // epilogue: C/D layout col=lane&15, row=(lane>>4)*4+reg [m89]
    int rowg = ti * 32 + rh * 16 + kg * 4;
    #pragma unroll
    for (int cc = 0; cc < 2; ++cc){
      #pragma unroll
      for (int reg = 0; reg < 4; ++reg)
        Hout[(size_t)(rowg + reg) * 64 + (cp * 2 + cc) * 16 + l15] = f2bf(acc[cc][reg]);
    }
    #pragma unroll
    for (int reg = 0; reg < 4; ++reg){
      int r = rowg + reg;
      #pragma unroll
      for (int cc = 0; cc < 2; ++cc){
        float ps = acc[cc][reg] * ascv[cc];
        float pd = acc[cc][reg] * adcv[cc];
        ps += __shfl_xor(ps, 1, 64); ps += __shfl_xor(ps, 2, 64); ps += __shfl_xor(ps, 4, 64);
        pd += __shfl_xor(pd, 1, 64); pd += __shfl_xor(pd, 2, 64); pd += __shfl_xor(pd, 4, 64);
        if ((l15 & 7) == 0){
          int head = (cp * 2 + cc) * 2 + (l15 >> 3);   // disjoint heads per wave
          alsrc[r * NH + head] = ps;
          aldst[r * NH + head] = pd;
        }
      }
    }
    cur ^= 1;
  }
}

// ---------------- layer-2 GEMM: A = pre-split bf16 planes, B in regs, dbuf stage --------
__global__ __launch_bounds__(256, 2) void k_gemm2(
    const unsigned short* __restrict__ Ah, const unsigned short* __restrict__ Al,
    const short* __restrict__ Bth, const short* __restrict__ Btl,
    const float* __restrict__ asrc, const float* __restrict__ adst,
    unsigned short* __restrict__ Hout, float* __restrict__ alsrc,
    float* __restrict__ aldst)
{
  __shared__ unsigned short abuf[2][2][64 * 64];  // [dbuf][plane][64r x 64c] = 32KB
  const int lane = threadIdx.x & 63;
  const int wave = threadIdx.x >> 6;
  const int l15 = lane & 15;
  const int kg = lane >> 4;
  const int rl = wave * 16 + l15;                 // full-row waves (c = 0..3)
  const int rs = rl & 7;

  short8 bh[2][4], bl[2][4];
  #pragma unroll
  for (int ks = 0; ks < 2; ++ks){
    #pragma unroll
    for (int c = 0; c < 4; ++c){
      unsigned boff = (unsigned)(c * 16 + l15) * C1 + ks * 32 + kg * 8;
      bh[ks][c] = *(const short8*)&Bth[boff];
      bl[ks][c] = *(const short8*)&Btl[boff];
    }
  }
  float ascv[4], adcv[4];
  #pragma unroll
  for (int c = 0; c < 4; ++c){
    ascv[c] = asrc[c * 16 + l15] * LOG2E;
    adcv[c] = adst[c * 16 + l15] * LOG2E;
  }

  const int t0 = blockIdx.x;
  // stage: 16 issues (q = wave*4+j): plane q>>3, row-block q&7 (8 rows x 128B = 1KB)
  auto stage = [&](int buf, int tile){
    #pragma unroll
    for (int j = 0; j < 4; ++j){
      int q = wave * 4 + j;
      int p = q >> 3, rb = q & 7;
      int r = rb * 8 + (lane >> 3);
      int rg = tile * 64 + r; if (rg > NNODES - 1) rg = NNODES - 1;
      unsigned u = (unsigned)((lane & 7) ^ (lane >> 3));   // (l&7)^(r&7)
      const unsigned short* src = (p ? Al : Ah) + (size_t)rg * 64 + u * 8;
      __builtin_amdgcn_global_load_lds(
          (const unsigned int*)src,
          (unsigned int*)&abuf[buf][p][rb * 512], 16, 0, 0);
    }
  };
  stage(0, t0);

  int cur = 0;
  for (int ti = t0; ti < NT2; ti += GGRID){
    __syncthreads();
    int nxt = ti + GGRID;
    if (nxt < NT2) stage(cur ^ 1, nxt);

    f32x4 acc[4] = {f32x4{0,0,0,0}, f32x4{0,0,0,0}, f32x4{0,0,0,0}, f32x4{0,0,0,0}};
    #pragma unroll
    for (int ks = 0; ks < 2; ++ks){
      unsigned U = (unsigned)(ks * 4 + kg);
      short8 ah = *(const short8*)&abuf[cur][0][rl * 64 + ((U ^ rs) << 3)];
      short8 al = *(const short8*)&abuf[cur][1][rl * 64 + ((U ^ rs) << 3)];
      #pragma unroll
      for (int c = 0; c < 4; ++c){
        acc[c] = __builtin_amdgcn_mfma_f32_16x16x32_bf16(ah, bh[ks][c], acc[c], 0, 0, 0);
        acc[c] = __builtin_amdgcn_mfma_f32_16x16x32_bf16(ah, bl[ks][c], acc[c], 0, 0, 0);
        acc[c] = __builtin_amdgcn_mfma_f32_16x16x32_bf16(al, bh[ks][c], acc[c], 0, 0, 0);
      }
    }

    int rowg = ti * 64 + wave * 16 + kg * 4;
    #pragma unroll
    for (int c = 0; c < 4; ++c){
      #pragma unroll
      for (int reg = 0; reg < 4; ++reg){
        int r = rowg + reg;
        if (r < NNODES) Hout[(size_t)r * 64 + c * 16 + l15] = f2bf(acc[c][reg]);
      }
    }
    #pragma unroll
    for (int reg = 0; reg < 4; ++reg){
      int r = rowg + reg;
      float ps = 0.0f, pd = 0.0f;
      #pragma unroll
      for (int c = 0; c < 4; ++c){
        ps = fmaf(acc[c][reg], ascv[c], ps);
        pd = fmaf(acc[c][reg], adcv[c], pd);
      }
      ps += __shfl_xor(ps, 1, 64); ps += __shfl_xor(ps, 2, 64);
      ps += __shfl_xor(ps, 4, 64); ps += __shfl_xor(ps, 8, 64);
      pd += __shfl_xor(pd, 1, 64); pd += __shfl_xor(pd, 2, 64);
      pd += __shfl_xor(pd, 4, 64); pd += __shfl_xor(pd, 8, 64);
      if (l15 == 0 && r < NNODES){ alsrc[r] = ps; aldst[r] = pd; }
    }
    cur ^= 1;
  }
}

// ---------------- aggregation: no-max softmax, 8-wide chunked MLP, one wave/node -------
template<int HEADS, bool DO_ELU, bool SPLIT_OUT>
__global__ __launch_bounds__(256) void k_agg(
    const int* __restrict__ rec, const int* __restrict__ rowptr,
    const unsigned short* __restrict__ hbuf,
    const float* __restrict__ alsrc, const float* __restrict__ aldst,
    const float* __restrict__ bias, float* __restrict__ outF,
    unsigned short* __restrict__ outH, unsigned short* __restrict__ outL){
  int tid = blockIdx.x * blockDim.x + threadIdx.x;
  int d = tid >> 6;
  int c = threadIdx.x & 63;
  if (d >= NNODES) return;
  d = __builtin_amdgcn_readfirstlane(d);      // wave-uniform -> scalar segment walk
  int beg = rowptr[d], end = rowptr[d + 1];
  int h = (HEADS == 8) ? (c >> 3) : 0;
  float ad = aldst[(size_t)d * HEADS + h];
  float s = 0.0f, acc = 0.0f;

  auto body = [&](int w, float a, float hv){
    float v = a + ad;
    v = fmaxf(v, v * SLOPE);                           // leakyrelu (slope<1)
    v += (float)(w >> 17) * (1.0f / QSCALE);           // corr (pre-scaled by log2e)
    v = fminf(v, 60.0f);                               // overflow guard
    float e = __builtin_amdgcn_exp2f(v);
    s += e;
    acc = fmaf(e, hv, acc);
  };

  int j = beg;
  for (; j + 8 <= end; j += 8){
    int w[8]; float a[8], hv[8];
    #pragma unroll
    for (int i = 0; i < 8; ++i) w[i] = rec[j + i];
    #pragma unroll
    for (int i = 0; i < 8; ++i){
      unsigned si = (unsigned)w[i] & 0x1FFFFu;
      a[i] = alsrc[si * HEADS + h];
      hv[i] = __uint_as_float((unsigned)hbuf[si * 64 + c] << 16);
    }
    #pragma unroll
    for (int i = 0; i < 8; ++i) body(w[i], a[i], hv[i]);
  }
  for (; j < end; ++j){
    int w = rec[j];
    unsigned sj = (unsigned)w & 0x1FFFFu;
    float a = alsrc[sj * HEADS + h];
    float hv = __uint_as_float((unsigned)hbuf[sj * 64 + c] << 16);
    body(w, a, hv);
  }

  float o = acc / (s + 1e-16f) + bias[c];
  if (DO_ELU) o = (o > 0.0f) ? o : (__expf(o) - 1.0f);
  if (SPLIT_OUT){
    unsigned u = __float_as_uint(o);
    outH[(size_t)d * 64 + c] = (unsigned short)(u >> 16);     // truncated hi
    float hf = __uint_as_float(u & 0xffff0000u);
    outL[(size_t)d * 64 + c] = (unsigned short)(__float_as_uint(o - hf) >> 16);
  } else {
    outF[(size_t)d * 64 + c] = o;
  }
}

extern "C" void kernel_launch(void* const* d_in, const int* in_sizes, int n_in,
                              void* d_out, int out_size, void* d_ws, size_t ws_size,
                              hipStream_t stream) {
  const float* x    = (const float*)d_in[0];
  const int*   ei   = (const int*)d_in[1];
  const float* ew   = (const float*)d_in[2];
  const float* W1   = (const float*)d_in[3];
  const float* as1  = (const float*)d_in[4];
  const float* ad1  = (const float*)d_in[5];
  const float* b1   = (const float*)d_in[6];
  const float* W2   = (const float*)d_in[7];
  const float* as2  = (const float*)d_in[8];
  const float* ad2  = (const float*)d_in[9];
  const float* b2   = (const float*)d_in[10];
  float* dout = (float*)d_out;

  float* ws = (float*)d_ws;
  size_t off = 0;
  auto alloc = [&](size_t nfloats) -> float* {
    float* p = ws + off;
    off += (nfloats + 15) & ~(size_t)15;
    return p;
  };
  unsigned short* h1 = (unsigned short*)alloc((size_t)NNODES * C1 / 2);  // bf16, 12.8MB
  unsigned short* o1h = (unsigned short*)alloc((size_t)NNODES * C1 / 2); // out1 hi plane
  unsigned short* o1l = (unsigned short*)alloc((size_t)NNODES * C1 / 2); // out1 lo plane
  float* alsrc1  = alloc((size_t)NNODES * NH);
  float* aldst1  = alloc((size_t)NNODES * NH);
  float* alsrc2  = alloc(NNODES);
  float* aldst2  = alloc(NNODES);
  int*   deg     = (int*)alloc(NNODES);
  int*   rowptr  = (int*)alloc(NNODES + 1);
  int*   rank    = (int*)alloc(EATOT);           // 6.8MB
  int*   partials= (int*)alloc(SCAN_BLOCKS + 16);
  int*   rec     = (int*)alloc(EATOT);           // 6.8MB packed records
  short* wt1h    = (short*)alloc(64 * FIN / 2);
  short* wt1l    = (short*)alloc(64 * FIN / 2);
  short* wt2h    = (short*)alloc(64 * C1 / 2);
  short* wt2l    = (short*)alloc(64 * C1 / 2);
  unsigned short* h2 = h1;   // h1 dead after k_agg1

  const int BS = 256;
  int egrid = (EATOT + BS - 1) / BS;
  int ngrid = (NNODES + BS - 1) / BS;

  // ---- weight splits ----
  hipLaunchKernelGGL(k_splitw, dim3((FIN * 64 + BS - 1) / BS), dim3(BS), 0, stream,
                     W1, wt1h, wt1l, FIN);
  hipLaunchKernelGGL(k_splitw, dim3((C1 * 64 + BS - 1) / BS), dim3(BS), 0, stream,
                     W2, wt2h, wt2l, C1);

  // ---- CSR build (dst-sorted, atomic-free placement) ----
  hipLaunchKernelGGL(k_zero,          dim3(ngrid), dim3(BS), 0, stream, deg);
  hipLaunchKernelGGL(k_hist,          dim3(egrid), dim3(BS), 0, stream, ei, deg, rank);
  hipLaunchKernelGGL(k_scan_partial,  dim3(SCAN_BLOCKS), dim3(BS), 0, stream, deg, partials);
  hipLaunchKernelGGL(k_scan_partials, dim3(1), dim3(128), 0, stream, partials);
  hipLaunchKernelGGL(k_scan_final,    dim3(SCAN_BLOCKS), dim3(BS), 0, stream, deg, partials, rowptr);
  hipLaunchKernelGGL(k_place,         dim3(egrid), dim3(BS), 0, stream, ei, ew, rank, rowptr, rec);

  int agrid = (NNODES * 64 + BS - 1) / BS;

  // ---- layer 1 ----
  hipLaunchKernelGGL(k_gemm1, dim3(GGRID), dim3(BS), 0, stream,
                     x, wt1h, wt1l, as1, ad1, h1, alsrc1, aldst1);
  hipLaunchKernelGGL((k_agg<NH, true, true>), dim3(agrid), dim3(BS), 0, stream,
                     rec, rowptr, h1, alsrc1, aldst1, b1, (float*)nullptr, o1h, o1l);

  // ---- layer 2 ----
  hipLaunchKernelGGL(k_gemm2, dim3(GGRID), dim3(BS), 0, stream,
                     o1h, o1l, wt2h, wt2l, as2, ad2, h2, alsrc2, aldst2);
  hipLaunchKernelGGL((k_agg<1, false, false>), dim3(agrid), dim3(BS), 0, stream,
                     rec, rowptr, h2, alsrc2, aldst2, b2, dout,
                     (unsigned short*)nullptr, (unsigned short*)nullptr);
}

// Round 11
// 221.483 us; speedup vs baseline: 1.4817x; 1.2517x over previous
//
#include <hip/hip_runtime.h>
#include <math.h>

#define NNODES 100000
#define NEDGES 1600000
#define EATOT  1700000   // edges + self loops
#define FIN    256
#define C1     64        // H*FH layer-1 output width
#define NH     8
#define C2     64
#define SLOPE  0.2f
#define LOG2E  1.4426950408889634f
#define QSCALE 8192.0f   // corr fixed-point scale (15-bit signed range)

#define NBKT  391        // ceil(NNODES / 256) dst-buckets
#define BCAP  5120       // bucket region capacity (expected 4348 +- 66; +11 sigma)
#define EPB_A 4096       // edges per block, pass A
#define NBLK_A 416       // ceil(EATOT / EPB_A)

#define NT1 3125         // gemm1 tiles (32 rows each, exact: 32*3125 = 100000)
#define NT2 1563         // gemm2 tiles (64 rows each)
#define GGRID 512        // grid for both gemms (2 blocks/CU resident)

typedef __attribute__((ext_vector_type(8))) short short8;
typedef __attribute__((ext_vector_type(4))) float f32x4;

__device__ __forceinline__ void edge_sdc(int e, const int* __restrict__ ei,
                                         const float* __restrict__ ew,
                                         int& s, int& d, float& corr){
  if (e < NEDGES){ s = ei[e]; d = ei[NEDGES + e]; corr = 1.0f - 1.0f / ew[e]; }
  else { s = e - NEDGES; d = s; corr = 0.0f; }
}

__device__ __forceinline__ unsigned short f2bf(float f){
  unsigned u = __float_as_uint(f);
  unsigned r = (u + 0x7FFFu + ((u >> 16) & 1u)) >> 16;   // RNE
  return (unsigned short)r;
}

// ---------------- bucket-sort CSR build (no per-edge device atomics) -------------------
__global__ void k_zero_gc(int* __restrict__ gcount){
  int t = threadIdx.x;
  if (t < NBKT) gcount[t] = 0;
}

// Pass A: partition edges into 391 dst-buckets. LDS-aggregated reservation:
// one global atomic per (block, bucket) instead of one per edge.
__global__ __launch_bounds__(256) void k_bucketA(
    const int* __restrict__ ei, const float* __restrict__ ew,
    int* __restrict__ gcount, uint2* __restrict__ brec){
  __shared__ int cnt[NBKT];
  __shared__ int base[NBKT];
  int t = threadIdx.x;
  for (int i = t; i < NBKT; i += 256) cnt[i] = 0;
  __syncthreads();
  int e0 = blockIdx.x * EPB_A;
  int e1 = e0 + EPB_A; if (e1 > EATOT) e1 = EATOT;
  for (int e = e0 + t; e < e1; e += 256){
    int d = (e < NEDGES) ? ei[NEDGES + e] : (e - NEDGES);
    atomicAdd(&cnt[d >> 8], 1);
  }
  __syncthreads();
  for (int i = t; i < NBKT; i += 256){
    int c = cnt[i];
    base[i] = c ? atomicAdd(&gcount[i], c) : 0;
    cnt[i] = 0;                                   // reuse as local cursor
  }
  __syncthreads();
  for (int e = e0 + t; e < e1; e += 256){
    int s, d; float corr;
    edge_sdc(e, ei, ew, s, d, corr);
    int bkt = d >> 8;
    int rel = base[bkt] + atomicAdd(&cnt[bkt], 1);
    int q = __float2int_rn(corr * (LOG2E * QSCALE));
    unsigned packed = ((unsigned)q << 17) | (unsigned)s;
    brec[(size_t)bkt * BCAP + rel] = make_uint2((unsigned)d, packed);
  }
}

// Pass S: exclusive scan of bucket counts -> bucket bases.
__global__ void k_bucketS(const int* __restrict__ gcount, int* __restrict__ gbase,
                          int* __restrict__ rowptr){
  __shared__ int sh[512];
  int t = threadIdx.x;
  int v = (t < NBKT) ? gcount[t] : 0;
  sh[t] = v; __syncthreads();
  for (int off = 1; off < 512; off <<= 1){
    int y = (t >= off) ? sh[t - off] : 0;
    __syncthreads();
    sh[t] += y;
    __syncthreads();
  }
  if (t < NBKT) gbase[t] = sh[t] - v;
  if (t == 0) rowptr[NNODES] = EATOT;
}

// Pass B: one block per bucket -- LDS histogram of 256 local nodes, block scan ->
// rowptr, LDS-cursor scatter of final packed records.
__global__ __launch_bounds__(256) void k_bucketB(
    const uint2* __restrict__ brec, const int* __restrict__ gcount,
    const int* __restrict__ gbase, int* __restrict__ rowptr, int* __restrict__ rec){
  __shared__ int hist[256];
  __shared__ int scanb[256];
  __shared__ int excl[256];
  __shared__ int cur[256];
  int bkt = blockIdx.x;
  int t = threadIdx.x;
  int n0 = bkt << 8;
  int cnt = gcount[bkt];
  int gb = gbase[bkt];
  hist[t] = 0;
  __syncthreads();
  const uint2* breg = brec + (size_t)bkt * BCAP;
  for (int j = t; j < cnt; j += 256)
    atomicAdd(&hist[breg[j].x & 255u], 1);
  __syncthreads();
  int h = hist[t];
  scanb[t] = h;
  __syncthreads();
  for (int off = 1; off < 256; off <<= 1){
    int y = (t >= off) ? scanb[t - off] : 0;
    __syncthreads();
    scanb[t] += y;
    __syncthreads();
  }
  int ex = scanb[t] - h;
  excl[t] = ex;
  cur[t] = 0;
  if (n0 + t < NNODES) rowptr[n0 + t] = gb + ex;
  __syncthreads();
  for (int j = t; j < cnt; j += 256){
    uint2 r = breg[j];
    int dl = (int)(r.x & 255u);
    int pos = gb + excl[dl] + atomicAdd(&cur[dl], 1);
    rec[pos] = (int)r.y;
  }
}

// ---------------- weight split: W[K][64] fp32 -> Wt_hi/Wt_lo[64][K] bf16 ----------------
__global__ void k_splitw(const float* __restrict__ W, short* __restrict__ th,
                         short* __restrict__ tl, int K){
  int idx = blockIdx.x * blockDim.x + threadIdx.x;
  if (idx >= K * 64) return;
  int k = idx >> 6, c = idx & 63;
  float w = W[idx];
  unsigned int b = __float_as_uint(w);
  unsigned short h = (unsigned short)(b >> 16);
  float hf = __uint_as_float(b & 0xffff0000u);
  float rem = w - hf;
  unsigned short lo = (unsigned short)(__float_as_uint(rem) >> 16);
  th[c * K + k] = (short)h;
  tl[c * K + k] = (short)lo;
}

// ---------------- layer-1 GEMM: zero VMEM in K-loop -------------------------------------
// B (W^T hi/lo) in registers via col-pair split: wave w -> rows (w>>1)*16.., cols (w&1)*32..
// x double-buffered via global_load_lds (32-row fp32 tiles), source-swizzled.
__global__ __launch_bounds__(256, 2) void k_gemm1(
    const float* __restrict__ X, const short* __restrict__ Bth,
    const short* __restrict__ Btl, const float* __restrict__ asrc,
    const float* __restrict__ adst, unsigned short* __restrict__ Hout,
    float* __restrict__ alsrc, float* __restrict__ aldst)
{
  __shared__ float xbuf[2][32 * 256];   // 2 x 32KB
  const int lane = threadIdx.x & 63;
  const int wave = threadIdx.x >> 6;
  const int l15 = lane & 15;
  const int kg = lane >> 4;
  const int cp = wave & 1;              // col-pair: cols cp*32 .. cp*32+31
  const int rh = wave >> 1;             // row-half: rows rh*16 .. rh*16+15
  const int rl = rh * 16 + l15;
  const int rs = rl & 7;

  // B fragments in registers (loaded once per block, L2-hot)
  short8 bh[8][2], bl[8][2];
  #pragma unroll
  for (int ks = 0; ks < 8; ++ks){
    #pragma unroll
    for (int cc = 0; cc < 2; ++cc){
      unsigned boff = (unsigned)((cp * 2 + cc) * 16 + l15) * FIN + ks * 32 + kg * 8;
      bh[ks][cc] = *(const short8*)&Bth[boff];
      bl[ks][cc] = *(const short8*)&Btl[boff];
    }
  }
  float ascv[2], adcv[2];
  #pragma unroll
  for (int cc = 0; cc < 2; ++cc){
    ascv[cc] = asrc[(cp * 2 + cc) * 16 + l15] * LOG2E;
    adcv[cc] = adst[(cp * 2 + cc) * 16 + l15] * LOG2E;
  }

  const int t0 = blockIdx.x;
  #pragma unroll
  for (int t = 0; t < 8; ++t){
    int r = wave * 8 + t;
    unsigned u = (unsigned)(lane ^ (r & 7));        // pre-swizzled source unit
    __builtin_amdgcn_global_load_lds(
        (const unsigned int*)(X + (size_t)(t0 * 32 + r) * FIN + u * 4),
        (unsigned int*)&xbuf[0][r * 256], 16, 0, 0);
  }

  int cur = 0;
  for (int ti = t0; ti < NT1; ti += GGRID){
    __syncthreads();                                 // buf[cur] ready (vmcnt drain)
    int nxt = ti + GGRID;
    if (nxt < NT1){                                  // async prefetch under compute
      #pragma unroll
      for (int t = 0; t < 8; ++t){
        int r = wave * 8 + t;
        unsigned u = (unsigned)(lane ^ (r & 7));
        __builtin_amdgcn_global_load_lds(
            (const unsigned int*)(X + (size_t)(nxt * 32 + r) * FIN + u * 4),
            (unsigned int*)&xbuf[cur ^ 1][r * 256], 16, 0, 0);
      }
    }

    f32x4 acc[2] = {f32x4{0,0,0,0}, f32x4{0,0,0,0}};
    #pragma unroll
    for (int ks = 0; ks < 8; ++ks){
      int k0 = ks * 32 + kg * 8;
      unsigned U = (unsigned)(k0 >> 2);              // 16B unit (even)
      float4 xa = *(const float4*)&xbuf[cur][rl * 256 + ((U ^ rs) << 2)];
      float4 xb = *(const float4*)&xbuf[cur][rl * 256 + (((U + 1) ^ rs) << 2)];
      float xs[8] = {xa.x, xa.y, xa.z, xa.w, xb.x, xb.y, xb.z, xb.w};
      short8 ah, al;
      #pragma unroll
      for (int j = 0; j < 8; ++j){
        unsigned u = __float_as_uint(xs[j]);
        ah[j] = (short)(u >> 16);
        float hf = __uint_as_float(u & 0xffff0000u);
        al[j] = (short)(__float_as_uint(xs[j] - hf) >> 16);
      }
      #pragma unroll
      for (int cc = 0; cc < 2; ++cc){
        acc[cc] = __builtin_amdgcn_mfma_f32_16x16x32_bf16(ah, bh[ks][cc], acc[cc], 0, 0, 0);
        acc[cc] = __builtin_amdgcn_mfma_f32_16x16x32_bf16(ah, bl[ks][cc], acc[cc], 0, 0, 0);
        acc[cc] = __builtin_amdgcn_mfma_f32_16x16x32_bf16(al, bh[ks][cc], acc[cc], 0, 0, 0);
      }
    }

    // epilogue: C/D layout col=lane&15, row=(lane>>4)*4+reg [m89]
    int rowg = ti * 32 + rh * 16 + kg * 4;
    #pragma unroll
    for (int cc = 0; cc < 2; ++cc){
      #pragma unroll
      for (int reg = 0; reg < 4; ++reg)
        Hout[(size_t)(rowg + reg) * 64 + (cp * 2 + cc) * 16 + l15] = f2bf(acc[cc][reg]);
    }
    #pragma unroll
    for (int reg = 0; reg < 4; ++reg){
      int r = rowg + reg;
      #pragma unroll
      for (int cc = 0; cc < 2; ++cc){
        float ps = acc[cc][reg] * ascv[cc];
        float pd = acc[cc][reg] * adcv[cc];
        ps += __shfl_xor(ps, 1, 64); ps += __shfl_xor(ps, 2, 64); ps += __shfl_xor(ps, 4, 64);
        pd += __shfl_xor(pd, 1, 64); pd += __shfl_xor(pd, 2, 64); pd += __shfl_xor(pd, 4, 64);
        if ((l15 & 7) == 0){
          int head = (cp * 2 + cc) * 2 + (l15 >> 3);   // disjoint heads per wave
          alsrc[r * NH + head] = ps;
          aldst[r * NH + head] = pd;
        }
      }
    }
    cur ^= 1;
  }
}

// ---------------- layer-2 GEMM: A = pre-split bf16 planes, B in regs, dbuf stage --------
__global__ __launch_bounds__(256, 2) void k_gemm2(
    const unsigned short* __restrict__ Ah, const unsigned short* __restrict__ Al,
    const short* __restrict__ Bth, const short* __restrict__ Btl,
    const float* __restrict__ asrc, const float* __restrict__ adst,
    unsigned short* __restrict__ Hout, float* __restrict__ alsrc,
    float* __restrict__ aldst)
{
  __shared__ unsigned short abuf[2][2][64 * 64];  // [dbuf][plane][64r x 64c] = 32KB
  const int lane = threadIdx.x & 63;
  const int wave = threadIdx.x >> 6;
  const int l15 = lane & 15;
  const int kg = lane >> 4;
  const int rl = wave * 16 + l15;                 // full-row waves (c = 0..3)
  const int rs = rl & 7;

  short8 bh[2][4], bl[2][4];
  #pragma unroll
  for (int ks = 0; ks < 2; ++ks){
    #pragma unroll
    for (int c = 0; c < 4; ++c){
      unsigned boff = (unsigned)(c * 16 + l15) * C1 + ks * 32 + kg * 8;
      bh[ks][c] = *(const short8*)&Bth[boff];
      bl[ks][c] = *(const short8*)&Btl[boff];
    }
  }
  float ascv[4], adcv[4];
  #pragma unroll
  for (int c = 0; c < 4; ++c){
    ascv[c] = asrc[c * 16 + l15] * LOG2E;
    adcv[c] = adst[c * 16 + l15] * LOG2E;
  }

  const int t0 = blockIdx.x;
  auto stage = [&](int buf, int tile){
    #pragma unroll
    for (int j = 0; j < 4; ++j){
      int q = wave * 4 + j;
      int p = q >> 3, rb = q & 7;
      int r = rb * 8 + (lane >> 3);
      int rg = tile * 64 + r; if (rg > NNODES - 1) rg = NNODES - 1;
      unsigned u = (unsigned)((lane & 7) ^ (lane >> 3));   // (l&7)^(r&7)
      const unsigned short* src = (p ? Al : Ah) + (size_t)rg * 64 + u * 8;
      __builtin_amdgcn_global_load_lds(
          (const unsigned int*)src,
          (unsigned int*)&abuf[buf][p][rb * 512], 16, 0, 0);
    }
  };
  stage(0, t0);

  int cur = 0;
  for (int ti = t0; ti < NT2; ti += GGRID){
    __syncthreads();
    int nxt = ti + GGRID;
    if (nxt < NT2) stage(cur ^ 1, nxt);

    f32x4 acc[4] = {f32x4{0,0,0,0}, f32x4{0,0,0,0}, f32x4{0,0,0,0}, f32x4{0,0,0,0}};
    #pragma unroll
    for (int ks = 0; ks < 2; ++ks){
      unsigned U = (unsigned)(ks * 4 + kg);
      short8 ah = *(const short8*)&abuf[cur][0][rl * 64 + ((U ^ rs) << 3)];
      short8 al = *(const short8*)&abuf[cur][1][rl * 64 + ((U ^ rs) << 3)];
      #pragma unroll
      for (int c = 0; c < 4; ++c){
        acc[c] = __builtin_amdgcn_mfma_f32_16x16x32_bf16(ah, bh[ks][c], acc[c], 0, 0, 0);
        acc[c] = __builtin_amdgcn_mfma_f32_16x16x32_bf16(ah, bl[ks][c], acc[c], 0, 0, 0);
        acc[c] = __builtin_amdgcn_mfma_f32_16x16x32_bf16(al, bh[ks][c], acc[c], 0, 0, 0);
      }
    }

    int rowg = ti * 64 + wave * 16 + kg * 4;
    #pragma unroll
    for (int c = 0; c < 4; ++c){
      #pragma unroll
      for (int reg = 0; reg < 4; ++reg){
        int r = rowg + reg;
        if (r < NNODES) Hout[(size_t)r * 64 + c * 16 + l15] = f2bf(acc[c][reg]);
      }
    }
    #pragma unroll
    for (int reg = 0; reg < 4; ++reg){
      int r = rowg + reg;
      float ps = 0.0f, pd = 0.0f;
      #pragma unroll
      for (int c = 0; c < 4; ++c){
        ps = fmaf(acc[c][reg], ascv[c], ps);
        pd = fmaf(acc[c][reg], adcv[c], pd);
      }
      ps += __shfl_xor(ps, 1, 64); ps += __shfl_xor(ps, 2, 64);
      ps += __shfl_xor(ps, 4, 64); ps += __shfl_xor(ps, 8, 64);
      pd += __shfl_xor(pd, 1, 64); pd += __shfl_xor(pd, 2, 64);
      pd += __shfl_xor(pd, 4, 64); pd += __shfl_xor(pd, 8, 64);
      if (l15 == 0 && r < NNODES){ alsrc[r] = ps; aldst[r] = pd; }
    }
    cur ^= 1;
  }
}

// ---------------- aggregation: no-max softmax, 8-wide chunked MLP, one wave/node -------
template<int HEADS, bool DO_ELU, bool SPLIT_OUT>
__global__ __launch_bounds__(256) void k_agg(
    const int* __restrict__ rec, const int* __restrict__ rowptr,
    const unsigned short* __restrict__ hbuf,
    const float* __restrict__ alsrc, const float* __restrict__ aldst,
    const float* __restrict__ bias, float* __restrict__ outF,
    unsigned short* __restrict__ outH, unsigned short* __restrict__ outL){
  int tid = blockIdx.x * blockDim.x + threadIdx.x;
  int d = tid >> 6;
  int c = threadIdx.x & 63;
  if (d >= NNODES) return;
  d = __builtin_amdgcn_readfirstlane(d);      // wave-uniform -> scalar segment walk
  int beg = rowptr[d], end = rowptr[d + 1];
  int h = (HEADS == 8) ? (c >> 3) : 0;
  float ad = aldst[(size_t)d * HEADS + h];
  float s = 0.0f, acc = 0.0f;

  auto body = [&](int w, float a, float hv){
    float v = a + ad;
    v = fmaxf(v, v * SLOPE);                           // leakyrelu (slope<1)
    v += (float)(w >> 17) * (1.0f / QSCALE);           // corr (pre-scaled by log2e)
    v = fminf(v, 60.0f);                               // overflow guard
    float e = __builtin_amdgcn_exp2f(v);
    s += e;
    acc = fmaf(e, hv, acc);
  };

  int j = beg;
  for (; j + 8 <= end; j += 8){
    int w[8]; float a[8], hv[8];
    #pragma unroll
    for (int i = 0; i < 8; ++i) w[i] = rec[j + i];
    #pragma unroll
    for (int i = 0; i < 8; ++i){
      unsigned si = (unsigned)w[i] & 0x1FFFFu;
      a[i] = alsrc[si * HEADS + h];
      hv[i] = __uint_as_float((unsigned)hbuf[si * 64 + c] << 16);
    }
    #pragma unroll
    for (int i = 0; i < 8; ++i) body(w[i], a[i], hv[i]);
  }
  for (; j < end; ++j){
    int w = rec[j];
    unsigned sj = (unsigned)w & 0x1FFFFu;
    float a = alsrc[sj * HEADS + h];
    float hv = __uint_as_float((unsigned)hbuf[sj * 64 + c] << 16);
    body(w, a, hv);
  }

  float o = acc / (s + 1e-16f) + bias[c];
  if (DO_ELU) o = (o > 0.0f) ? o : (__expf(o) - 1.0f);
  if (SPLIT_OUT){
    unsigned u = __float_as_uint(o);
    outH[(size_t)d * 64 + c] = (unsigned short)(u >> 16);     // truncated hi
    float hf = __uint_as_float(u & 0xffff0000u);
    outL[(size_t)d * 64 + c] = (unsigned short)(__float_as_uint(o - hf) >> 16);
  } else {
    outF[(size_t)d * 64 + c] = o;
  }
}

extern "C" void kernel_launch(void* const* d_in, const int* in_sizes, int n_in,
                              void* d_out, int out_size, void* d_ws, size_t ws_size,
                              hipStream_t stream) {
  const float* x    = (const float*)d_in[0];
  const int*   ei   = (const int*)d_in[1];
  const float* ew   = (const float*)d_in[2];
  const float* W1   = (const float*)d_in[3];
  const float* as1  = (const float*)d_in[4];
  const float* ad1  = (const float*)d_in[5];
  const float* b1   = (const float*)d_in[6];
  const float* W2   = (const float*)d_in[7];
  const float* as2  = (const float*)d_in[8];
  const float* ad2  = (const float*)d_in[9];
  const float* b2   = (const float*)d_in[10];
  float* dout = (float*)d_out;

  float* ws = (float*)d_ws;
  size_t off = 0;
  auto alloc = [&](size_t nfloats) -> float* {
    float* p = ws + off;
    off += (nfloats + 15) & ~(size_t)15;
    return p;
  };
  unsigned short* h1 = (unsigned short*)alloc((size_t)NNODES * C1 / 2);  // bf16, 12.8MB
  unsigned short* o1h = (unsigned short*)alloc((size_t)NNODES * C1 / 2); // out1 hi plane
  unsigned short* o1l = (unsigned short*)alloc((size_t)NNODES * C1 / 2); // out1 lo plane
  float* alsrc1  = alloc((size_t)NNODES * NH);
  float* aldst1  = alloc((size_t)NNODES * NH);
  float* alsrc2  = alloc(NNODES);
  float* aldst2  = alloc(NNODES);
  int*   gcount  = (int*)alloc(NBKT + 16);
  int*   gbase   = (int*)alloc(NBKT + 16);
  int*   rowptr  = (int*)alloc(NNODES + 1);
  int*   rec     = (int*)alloc(EATOT);                    // 6.8MB packed records
  uint2* brec    = (uint2*)alloc((size_t)NBKT * BCAP * 2); // 16MB bucket staging
  short* wt1h    = (short*)alloc(64 * FIN / 2);
  short* wt1l    = (short*)alloc(64 * FIN / 2);
  short* wt2h    = (short*)alloc(64 * C1 / 2);
  short* wt2l    = (short*)alloc(64 * C1 / 2);
  unsigned short* h2 = h1;   // h1 dead after k_agg1

  const int BS = 256;

  // ---- weight splits ----
  hipLaunchKernelGGL(k_splitw, dim3((FIN * 64 + BS - 1) / BS), dim3(BS), 0, stream,
                     W1, wt1h, wt1l, FIN);
  hipLaunchKernelGGL(k_splitw, dim3((C1 * 64 + BS - 1) / BS), dim3(BS), 0, stream,
                     W2, wt2h, wt2l, C1);

  // ---- CSR build: bucket sort (no per-edge device atomics) ----
  hipLaunchKernelGGL(k_zero_gc, dim3(1), dim3(512), 0, stream, gcount);
  hipLaunchKernelGGL(k_bucketA, dim3(NBLK_A), dim3(BS), 0, stream, ei, ew, gcount, brec);
  hipLaunchKernelGGL(k_bucketS, dim3(1), dim3(512), 0, stream, gcount, gbase, rowptr);
  hipLaunchKernelGGL(k_bucketB, dim3(NBKT), dim3(BS), 0, stream,
                     brec, gcount, gbase, rowptr, rec);

  int agrid = (NNODES * 64 + BS - 1) / BS;

  // ---- layer 1 ----
  hipLaunchKernelGGL(k_gemm1, dim3(GGRID), dim3(BS), 0, stream,
                     x, wt1h, wt1l, as1, ad1, h1, alsrc1, aldst1);
  hipLaunchKernelGGL((k_agg<NH, true, true>), dim3(agrid), dim3(BS), 0, stream,
                     rec, rowptr, h1, alsrc1, aldst1, b1, (float*)nullptr, o1h, o1l);

  // ---- layer 2 ----
  hipLaunchKernelGGL(k_gemm2, dim3(GGRID), dim3(BS), 0, stream,
                     o1h, o1l, wt2h, wt2l, as2, ad2, h2, alsrc2, aldst2);
  hipLaunchKernelGGL((k_agg<1, false, false>), dim3(agrid), dim3(BS), 0, stream,
                     rec, rowptr, h2, alsrc2, aldst2, b2, dout,
                     (unsigned short*)nullptr, (unsigned short*)nullptr);
}